// Round 1
// baseline (257.628 us; speedup 1.0000x reference)
//
#include <hip/hip_runtime.h>
#include <hip/hip_bf16.h>
#include <stdint.h>

#define HIDDEN 1024
#define NHEADS 16
#define HDIM   64
#define BSZ    4
#define QLEN   1024
#define KVLEN  2048

typedef __bf16 bf16_t;
typedef __bf16 bf16x8 __attribute__((ext_vector_type(8)));
typedef __bf16 bf16x4 __attribute__((ext_vector_type(4)));
typedef float  f32x4  __attribute__((ext_vector_type(4)));

__device__ __forceinline__ float clamp50(float v) {
    return fminf(fmaxf(v, -50.f), 50.f);
}

// ---------------------------------------------------------------------------
// Mask preparation with dtype auto-detection (bool/uint8 vs int32 vs float32).
// Writes maskf[b*KVLEN + k] = 1.0f (masked) / 0.0f.
// Detection over first 2048 u32 words (== 8192 bytes, valid for all layouts):
//   float32: words are 0x3F800000 or 0
//   int32:   words are 1 or 0 (no high bytes)
//   uint8:   ~27% of words have nonzero bytes above byte0
// ---------------------------------------------------------------------------
__global__ void mask_prep_kernel(const void* __restrict__ raw, float* __restrict__ maskf) {
    __shared__ int s_float, s_multi;
    const int t = threadIdx.x;
    if (t == 0) { s_float = 0; s_multi = 0; }
    __syncthreads();
    const uint32_t* w = (const uint32_t*)raw;
    int cf = 0, cm = 0;
    for (int i = t; i < 2048; i += blockDim.x) {
        uint32_t v = w[i];
        if (v == 0x3F800000u) cf++;
        else if (v & 0xFFFFFF00u) cm++;
    }
    if (cf) atomicAdd(&s_float, cf);
    if (cm) atomicAdd(&s_multi, cm);
    __syncthreads();
    const int mode = (s_float > 0) ? 2 : ((s_multi > 0) ? 0 : 1);
    for (int i = t; i < BSZ * KVLEN; i += blockDim.x) {
        bool m;
        if (mode == 2)      m = ((const float*)raw)[i] != 0.0f;
        else if (mode == 1) m = ((const int*)raw)[i] != 0;
        else                m = ((const unsigned char*)raw)[i] != 0;
        maskf[i] = m ? 1.0f : 0.0f;
    }
}

// ---------------------------------------------------------------------------
// fp32 -> bf16 with clamp(+-50)  (vectorized float4 in, bf16x4 out)
// ---------------------------------------------------------------------------
__global__ void cvt_clamp_kernel(const float* __restrict__ src, bf16_t* __restrict__ dst, int n4) {
    int i = blockIdx.x * blockDim.x + threadIdx.x;
    if (i >= n4) return;
    const float4 v = ((const float4*)src)[i];
    bf16x4 o;
    o[0] = (bf16_t)clamp50(v.x);
    o[1] = (bf16_t)clamp50(v.y);
    o[2] = (bf16_t)clamp50(v.z);
    o[3] = (bf16_t)clamp50(v.w);
    ((bf16x4*)dst)[i] = o;
}

// ---------------------------------------------------------------------------
// NT GEMM: C[m][n] = clamp50( sum_k A[m][k]*B[n][k] + bias[n] )
// A: [M][1024] bf16 row-major, B: [1024][1024] bf16 (weight, row-major = [n][k])
// 128x128 block tile, BK=64, 4 waves (2x2), 16x16x32 bf16 MFMA.
// LDS tiles XOR-swizzled: element (r,k) at byte r*128 + ((k*2) ^ ((r&7)<<4)).
// EPI 0: bf16 out in per-head layout [(b*16+h)][s][d], seqlen = 1<<slog
// EPI 1: fp32 out [M][1024]
// ---------------------------------------------------------------------------
template <int EPI>
__global__ __launch_bounds__(256)
void gemm_bt_kernel(const bf16_t* __restrict__ A, const bf16_t* __restrict__ B,
                    const float* __restrict__ bias, void* __restrict__ out, int slog)
{
    constexpr int K = HIDDEN;
    __shared__ __align__(16) bf16_t Als[128 * 64];
    __shared__ __align__(16) bf16_t Bls[128 * 64];

    const int m0 = blockIdx.y * 128;
    const int n0 = blockIdx.x * 128;
    const int t = threadIdx.x;
    const int wave = t >> 6, lane = t & 63;
    const int wm = wave >> 1, wn = wave & 1;

    f32x4 acc[4][4] = {};

    const char* Ab = (const char*)A + (size_t)m0 * (K * 2);
    const char* Bb = (const char*)B + (size_t)n0 * (K * 2);
    const int sr = wave * 8 + (lane >> 3);  // staging row (+ i*32)
    const int sc = lane & 7;                // 16B chunk in 128B row

    for (int kt = 0; kt < K / 64; ++kt) {
        bf16x8 ar[4], br[4];
#pragma unroll
        for (int i = 0; i < 4; ++i) {
            const int row = i * 32 + sr;
            ar[i] = *(const bf16x8*)(Ab + (size_t)row * (K * 2) + kt * 128 + (sc << 4));
            br[i] = *(const bf16x8*)(Bb + (size_t)row * (K * 2) + kt * 128 + (sc << 4));
        }
#pragma unroll
        for (int i = 0; i < 4; ++i) {
            const int row = i * 32 + sr;
            const int wo = row * 128 + ((sc ^ (row & 7)) << 4);
            *(bf16x8*)((char*)Als + wo) = ar[i];
            *(bf16x8*)((char*)Bls + wo) = br[i];
        }
        __syncthreads();
#pragma unroll
        for (int kc = 0; kc < 2; ++kc) {
            const int kbyte = kc * 64 + ((lane >> 4) << 4);  // k*2 byte offset
            bf16x8 af[4], bfr[4];
#pragma unroll
            for (int f = 0; f < 4; ++f) {
                const int arow = wm * 64 + f * 16 + (lane & 15);
                af[f] = *(const bf16x8*)((const char*)Als + arow * 128 + (kbyte ^ ((arow & 7) << 4)));
                const int brow = wn * 64 + f * 16 + (lane & 15);
                bfr[f] = *(const bf16x8*)((const char*)Bls + brow * 128 + (kbyte ^ ((brow & 7) << 4)));
            }
#pragma unroll
            for (int mf = 0; mf < 4; ++mf)
#pragma unroll
                for (int nf = 0; nf < 4; ++nf)
                    acc[mf][nf] = __builtin_amdgcn_mfma_f32_16x16x32_bf16(af[mf], bfr[nf], acc[mf][nf], 0, 0, 0);
        }
        __syncthreads();
    }

    // epilogue: D row = (lane>>4)*4 + r, col = lane&15  [m89/m91-verified]
#pragma unroll
    for (int mf = 0; mf < 4; ++mf) {
#pragma unroll
        for (int nf = 0; nf < 4; ++nf) {
            const int gn = n0 + wn * 64 + nf * 16 + (lane & 15);
            const float bv = bias[gn];
#pragma unroll
            for (int r = 0; r < 4; ++r) {
                const int gm = m0 + wm * 64 + mf * 16 + ((lane >> 4) << 2) + r;
                const float v = clamp50(acc[mf][nf][r] + bv);
                if (EPI == 0) {
                    const int b = gm >> slog;
                    const int s = gm & ((1 << slog) - 1);
                    const int h = gn >> 6, d = gn & 63;
                    ((bf16_t*)out)[((((size_t)(b * NHEADS + h)) << slog) + s) * HDIM + d] = (bf16_t)v;
                } else {
                    ((float*)out)[(size_t)gm * HIDDEN + gn] = v;
                }
            }
        }
    }
}

// ---------------------------------------------------------------------------
// per-head transpose: vh[bh][s][64] -> vt[bh][64][s]   (s = KVLEN)
// ---------------------------------------------------------------------------
__global__ void transpose_v_kernel(const bf16_t* __restrict__ vh, bf16_t* __restrict__ vt) {
    __shared__ __align__(16) bf16_t tile[64][72];
    const int bh = blockIdx.y;
    const int s0 = blockIdx.x * 64;
    const int t = threadIdx.x;
    const int row = t >> 2;            // 0..63
    const int col = (t & 3) << 4;      // 0,16,32,48
    const bf16_t* src = vh + ((size_t)bh * KVLEN + (s0 + row)) * HDIM + col;
    *(bf16x8*)&tile[row][col]     = *(const bf16x8*)src;
    *(bf16x8*)&tile[row][col + 8] = *(const bf16x8*)(src + 8);
    __syncthreads();
    bf16x8 o0, o1;
#pragma unroll
    for (int j = 0; j < 8; ++j) { o0[j] = tile[col + j][row]; o1[j] = tile[col + 8 + j][row]; }
    bf16_t* dst = vt + ((size_t)bh * HDIM + row) * KVLEN + s0 + col;
    *(bf16x8*)dst       = o0;
    *(bf16x8*)(dst + 8) = o1;
}

// ---------------------------------------------------------------------------
// Flash attention. Grid (16 q-tiles, 64 bh). 4 waves, each owns 16 q-rows.
// Qh: [bh][1024][64], Kh: [bh][2048][64], Vt: [bh][64][2048], all bf16.
// scores = clip(QK^T/8, +-80); masked -> -10000; online softmax; O = P V.
// K/V tiles + per-wave P staged in LDS with the same XOR swizzle as GEMM.
// ---------------------------------------------------------------------------
__global__ __launch_bounds__(256)
void attn_fwd_kernel(const bf16_t* __restrict__ Qh, const bf16_t* __restrict__ Kh,
                     const bf16_t* __restrict__ Vt, const float* __restrict__ maskf,
                     bf16_t* __restrict__ aout)
{
    __shared__ __align__(16) bf16_t Kls[64 * 64];      // [key][d] swizzled
    __shared__ __align__(16) bf16_t Vls[64 * 64];      // [d][key] swizzled
    __shared__ __align__(16) bf16_t Pls[4][16 * 64];   // per-wave P [qrow][key] swizzled
    const int qt = blockIdx.x;
    const int bh = blockIdx.y;
    const int b = bh >> 4, h = bh & 15;
    const int t = threadIdx.x, wave = t >> 6, lane = t & 63;

    // Hoisted Q A-fragments: row = lane&15, k(d) = dh*32 + (lane>>4)*8
    const int qrow_in = qt * 64 + wave * 16 + (lane & 15);
    const bf16_t* qp = Qh + ((size_t)bh * QLEN + qrow_in) * HDIM + ((lane >> 4) << 3);
    const bf16x8 qf0 = *(const bf16x8*)qp;
    const bf16x8 qf1 = *(const bf16x8*)(qp + 32);

    f32x4 oacc[4] = {};                           // 4 d-blocks of 16
    float mrun[4] = {-1e30f, -1e30f, -1e30f, -1e30f};
    float lrun[4] = {0.f, 0.f, 0.f, 0.f};

    const int sr = wave * 8 + (lane >> 3);
    const int sc = lane & 7;
    const char* Kb = (const char*)(Kh + (size_t)bh * KVLEN * HDIM);
    const char* Vb = (const char*)(Vt + (size_t)bh * HDIM * KVLEN);
    const float* mrow = maskf + b * KVLEN;
    char* Pb = (char*)(&Pls[wave][0]);

    for (int kt = 0; kt < KVLEN / 64; ++kt) {
        // ---- stage K tile [64 keys][64 d] and V^T tile [64 d][64 keys]
        bf16x8 kr[2], vr[2];
#pragma unroll
        for (int i = 0; i < 2; ++i) {
            const int row = i * 32 + sr;
            kr[i] = *(const bf16x8*)(Kb + (size_t)(kt * 64 + row) * 128 + (sc << 4));
            vr[i] = *(const bf16x8*)(Vb + (size_t)row * (KVLEN * 2) + (size_t)kt * 128 + (sc << 4));
        }
#pragma unroll
        for (int i = 0; i < 2; ++i) {
            const int row = i * 32 + sr;
            const int wo = row * 128 + ((sc ^ (row & 7)) << 4);
            *(bf16x8*)((char*)Kls + wo) = kr[i];
            *(bf16x8*)((char*)Vls + wo) = vr[i];
        }
        __syncthreads();

        // ---- S = Q K^T : 4 key-blocks of 16, K=64 split in 2 MFMAs
        f32x4 sacc[4] = {};
#pragma unroll
        for (int kb = 0; kb < 4; ++kb) {
            const int key = kb * 16 + (lane & 15);
            const int rowoff = key * 128;
            const int sw = (key & 7) << 4;
            const int kb0 = (lane >> 4) << 4;
            const bf16x8 kf0 = *(const bf16x8*)((const char*)Kls + rowoff + ((kb0)      ^ sw));
            const bf16x8 kf1 = *(const bf16x8*)((const char*)Kls + rowoff + ((kb0 + 64) ^ sw));
            sacc[kb] = __builtin_amdgcn_mfma_f32_16x16x32_bf16(qf0, kf0, sacc[kb], 0, 0, 0);
            sacc[kb] = __builtin_amdgcn_mfma_f32_16x16x32_bf16(qf1, kf1, sacc[kb], 0, 0, 0);
        }

        // ---- mask / scale / clip + online softmax (wave-parallel)
        float mv[4];
#pragma unroll
        for (int kb = 0; kb < 4; ++kb)
            mv[kb] = mrow[kt * 64 + kb * 16 + (lane & 15)];

        float pv[4][4];
#pragma unroll
        for (int r = 0; r < 4; ++r) {
            float s0 = fminf(fmaxf(sacc[0][r] * 0.125f, -80.f), 80.f);
            float s1 = fminf(fmaxf(sacc[1][r] * 0.125f, -80.f), 80.f);
            float s2 = fminf(fmaxf(sacc[2][r] * 0.125f, -80.f), 80.f);
            float s3 = fminf(fmaxf(sacc[3][r] * 0.125f, -80.f), 80.f);
            s0 = (mv[0] != 0.f) ? -10000.f : s0;
            s1 = (mv[1] != 0.f) ? -10000.f : s1;
            s2 = (mv[2] != 0.f) ? -10000.f : s2;
            s3 = (mv[3] != 0.f) ? -10000.f : s3;
            float mx = fmaxf(fmaxf(s0, s1), fmaxf(s2, s3));
#pragma unroll
            for (int off = 1; off < 16; off <<= 1)
                mx = fmaxf(mx, __shfl_xor(mx, off));
            const float mi = fmaxf(mrun[r], mx);
            const float scale = __expf(mrun[r] - mi);
            const float p0 = __expf(s0 - mi), p1 = __expf(s1 - mi);
            const float p2 = __expf(s2 - mi), p3 = __expf(s3 - mi);
            float ps = p0 + p1 + p2 + p3;
#pragma unroll
            for (int off = 1; off < 16; off <<= 1)
                ps += __shfl_xor(ps, off);
            lrun[r] = lrun[r] * scale + ps;
            mrun[r] = mi;
#pragma unroll
            for (int db = 0; db < 4; ++db) oacc[db][r] *= scale;
            pv[r][0] = p0; pv[r][1] = p1; pv[r][2] = p2; pv[r][3] = p3;
        }

        // ---- P -> per-wave LDS tile (bf16, swizzled rows of 128B)
        {
            const int rbase = (lane >> 4) << 2;
#pragma unroll
            for (int r = 0; r < 4; ++r) {
                const int prow = rbase + r;
                const int sw = (prow & 7) << 4;
                const int rowoff = prow * 128;
#pragma unroll
                for (int kb = 0; kb < 4; ++kb) {
                    const int key = kb * 16 + (lane & 15);
                    *(bf16_t*)(Pb + rowoff + ((key * 2) ^ sw)) = (bf16_t)pv[r][kb];
                }
            }
        }

        // ---- O += P V  (A = P [16 q][64 k], B from V^T tile)
#pragma unroll
        for (int db = 0; db < 4; ++db) {
            const int vrow = db * 16 + (lane & 15);
            const int vsw = (vrow & 7) << 4;
#pragma unroll
            for (int kc = 0; kc < 2; ++kc) {
                const int kbyte = kc * 64 + ((lane >> 4) << 4);
                const int prow = lane & 15;
                const bf16x8 pf = *(const bf16x8*)(Pb + prow * 128 + (kbyte ^ ((prow & 7) << 4)));
                const bf16x8 vf = *(const bf16x8*)((const char*)Vls + vrow * 128 + (kbyte ^ vsw));
                oacc[db] = __builtin_amdgcn_mfma_f32_16x16x32_bf16(pf, vf, oacc[db], 0, 0, 0);
            }
        }
        __syncthreads();   // protect K/V tiles before next staging
    }

    // ---- epilogue: out[b][q][h*64+d] = O / l
    const int rbase = (lane >> 4) << 2;
#pragma unroll
    for (int db = 0; db < 4; ++db) {
        const int d = db * 16 + (lane & 15);
#pragma unroll
        for (int r = 0; r < 4; ++r) {
            const int qrow = qt * 64 + wave * 16 + rbase + r;
            const float v = oacc[db][r] / lrun[r];
            aout[((size_t)(b * QLEN + qrow)) * HIDDEN + h * HDIM + d] = (bf16_t)v;
        }
    }
}

// ---------------------------------------------------------------------------
extern "C" void kernel_launch(void* const* d_in, const int* in_sizes, int n_in,
                              void* d_out, int out_size, void* d_ws, size_t ws_size,
                              hipStream_t stream) {
    (void)in_sizes; (void)n_in; (void)out_size; (void)ws_size;
    const float* q   = (const float*)d_in[0];
    const float* kv  = (const float*)d_in[1];
    const void*  msk = d_in[2];
    const float* Wq  = (const float*)d_in[3];
    const float* bq  = (const float*)d_in[4];
    const float* Wk  = (const float*)d_in[5];
    const float* bk  = (const float*)d_in[6];
    const float* Wv  = (const float*)d_in[7];
    const float* bv  = (const float*)d_in[8];
    const float* Wo  = (const float*)d_in[9];
    const float* bo  = (const float*)d_in[10];

    char* ws = (char*)d_ws;
    const size_t MB = 1024 * 1024;
    float*  maskf = (float*)ws;                           // 32 KB
    bf16_t* q_bf  = (bf16_t*)(ws + 32 * 1024);            // 8 MB   (dead after qh GEMM)
    bf16_t* kv_bf = (bf16_t*)(ws + 32 * 1024 + 8  * MB);  // 16 MB  (reused as vt)
    bf16_t* wq_bf = (bf16_t*)(ws + 32 * 1024 + 24 * MB);  // 2 MB
    bf16_t* wk_bf = (bf16_t*)(ws + 32 * 1024 + 26 * MB);
    bf16_t* wv_bf = (bf16_t*)(ws + 32 * 1024 + 28 * MB);
    bf16_t* wo_bf = (bf16_t*)(ws + 32 * 1024 + 30 * MB);
    bf16_t* qh    = (bf16_t*)(ws + 32 * 1024 + 32 * MB);  // 8 MB
    bf16_t* kh    = (bf16_t*)(ws + 32 * 1024 + 40 * MB);  // 16 MB
    bf16_t* vh    = (bf16_t*)(ws + 32 * 1024 + 56 * MB);  // 16 MB (reused as aout) -> end 72 MB
    bf16_t* vt    = kv_bf;   // kv_bf dead once kh/vh GEMMs complete
    bf16_t* aout  = vh;      // vh dead once transpose completes

    mask_prep_kernel<<<1, 1024, 0, stream>>>(msk, maskf);

    cvt_clamp_kernel<<<dim3(4096), dim3(256), 0, stream>>>(q,  q_bf,  (BSZ * QLEN  * HIDDEN) / 4);
    cvt_clamp_kernel<<<dim3(8192), dim3(256), 0, stream>>>(kv, kv_bf, (BSZ * KVLEN * HIDDEN) / 4);
    cvt_clamp_kernel<<<dim3(1024), dim3(256), 0, stream>>>(Wq, wq_bf, (HIDDEN * HIDDEN) / 4);
    cvt_clamp_kernel<<<dim3(1024), dim3(256), 0, stream>>>(Wk, wk_bf, (HIDDEN * HIDDEN) / 4);
    cvt_clamp_kernel<<<dim3(1024), dim3(256), 0, stream>>>(Wv, wv_bf, (HIDDEN * HIDDEN) / 4);
    cvt_clamp_kernel<<<dim3(1024), dim3(256), 0, stream>>>(Wo, wo_bf, (HIDDEN * HIDDEN) / 4);

    gemm_bt_kernel<0><<<dim3(8, 32), 256, 0, stream>>>(q_bf,  wq_bf, bq, qh, 10);
    gemm_bt_kernel<0><<<dim3(8, 64), 256, 0, stream>>>(kv_bf, wk_bf, bk, kh, 11);
    gemm_bt_kernel<0><<<dim3(8, 64), 256, 0, stream>>>(kv_bf, wv_bf, bv, vh, 11);

    transpose_v_kernel<<<dim3(32, 64), 256, 0, stream>>>(vh, vt);

    attn_fwd_kernel<<<dim3(16, 64), 256, 0, stream>>>(qh, kh, vt, maskf, aout);

    gemm_bt_kernel<1><<<dim3(8, 32), 256, 0, stream>>>(aout, wo_bf, bo, d_out, 10);
}